// Round 20
// baseline (605.372 us; speedup 1.0000x reference)
//
#include <hip/hip_runtime.h>
#include <hip/hip_bf16.h>
#include <math.h>

#define BATCH 4096
#define NNEG 32768
#define HID 1024
#define PROJ 256
#define TOPK 128
#define ROWS_TOTAL 40960
#define CHUNK 2048
#define INV_T 14.2857142857142857f  // 1/0.07

#define BM 128
#define BN 128
#define BK 64

#define BNS_ROWS 128   // rows per bn_stats_partial block

typedef __attribute__((ext_vector_type(8))) short bf16x8;
typedef __attribute__((ext_vector_type(4))) float f32x4;

// ---------- helpers ----------
__device__ __forceinline__ float b2f(unsigned short u) {
    return __uint_as_float(((unsigned)u) << 16);
}
__device__ __forceinline__ unsigned short f2b(float f) {
    unsigned u = __float_as_uint(f);
    unsigned r = (u + 0x7FFFu + ((u >> 16) & 1u)) >> 16;  // RNE
    return (unsigned short)r;
}
// branchless tanh-GELU, exp2 form
__device__ __forceinline__ float gelu_fast(float v) {
    float v2 = v * v;
    float w = v * fmaf(v2, -0.1029433f, -2.3022086f);
    float e = exp2f(w);
    return v * __builtin_amdgcn_rcpf(1.0f + e);
}

__device__ __forceinline__ float blockReduceSumF(float v, volatile float* scratch) {
    #pragma unroll
    for (int o = 32; o > 0; o >>= 1) v += __shfl_down(v, o);
    int wid = threadIdx.x >> 6, lane = threadIdx.x & 63;
    __syncthreads();
    if (lane == 0) scratch[wid] = v;
    __syncthreads();
    return scratch[0] + scratch[1] + scratch[2] + scratch[3];
}
__device__ __forceinline__ int blockReduceSumI(int v, volatile int* scratch) {
    #pragma unroll
    for (int o = 32; o > 0; o >>= 1) v += __shfl_down(v, o);
    int wid = threadIdx.x >> 6, lane = threadIdx.x & 63;
    __syncthreads();
    if (lane == 0) scratch[wid] = v;
    __syncthreads();
    return scratch[0] + scratch[1] + scratch[2] + scratch[3];
}

// async global->LDS, 16B per lane; lds base must be wave-uniform
__device__ __forceinline__ void gl_lds16(const unsigned short* g, unsigned short* l) {
    __builtin_amdgcn_global_load_lds(
        (const __attribute__((address_space(1))) unsigned*)g,
        (__attribute__((address_space(3))) unsigned*)l, 16, 0, 0);
}

// ---------- fp32 -> bf16 conversion ----------
__global__ __launch_bounds__(256) void conv_f2b(const float* __restrict__ src,
                                                unsigned short* __restrict__ dst, int n)
{
    int i = (blockIdx.x * 256 + threadIdx.x) * 4;
    if (i + 3 < n) {
        float4 v = *(const float4*)(src + i);
        ushort4 o;
        o.x = f2b(v.x); o.y = f2b(v.y); o.z = f2b(v.z); o.w = f2b(v.w);
        *(ushort4*)(dst + i) = o;
    }
}

__global__ __launch_bounds__(256) void conv_f2b8(const float* __restrict__ src,
                                                 unsigned short* __restrict__ dst)
{
    int i = (blockIdx.x * 256 + threadIdx.x) * 8;
    float4 a = *(const float4*)(src + i);
    float4 b = *(const float4*)(src + i + 4);
    ushort4 o0, o1;
    o0.x = f2b(a.x); o0.y = f2b(a.y); o0.z = f2b(a.z); o0.w = f2b(a.w);
    o1.x = f2b(b.x); o1.y = f2b(b.y); o1.z = f2b(b.z); o1.w = f2b(b.w);
    *(ushort4*)(dst + i) = o0;
    *(ushort4*)(dst + i + 4) = o1;
}

// ---------- XCD-chunked bijective swizzle (nwg % 8 == 0 in all launches) ----------
__device__ __forceinline__ void xcd_swizzle(int& bx, int& by) {
    int gx = gridDim.x;
    int orig = by * gx + bx;
    int q = (gx * gridDim.y) >> 3;
    int wg = (orig & 7) * q + (orig >> 3);
    bx = wg % gx;
    by = wg / gx;
}

// ---------- MFMA GEMM (R17-proven: single-buffer BK=64, 4 waves/SIMD) ----------
__global__ __launch_bounds__(256, 4) void mfma_gemm(
    const unsigned short* __restrict__ A, const unsigned short* __restrict__ Bw,
    const float* __restrict__ bias, unsigned short* __restrict__ C,
    int M, int N, int K)
{
    __shared__ unsigned short As[BM * BK];
    __shared__ unsigned short Bs[BN * BK];
    const int tid = threadIdx.x;
    int bxi = blockIdx.x, byi = blockIdx.y;
    xcd_swizzle(bxi, byi);
    const int bm = byi * BM;
    const int bn = bxi * BN;
    const int wave = tid >> 6;
    const int lane = tid & 63;
    const int wm = (wave >> 1) * 64;
    const int wn = (wave & 1) * 64;
    const int fr = lane & 15;
    const int fg = lane >> 4;

    int s_slot[4], s_row[4], s_c16[4];
    #pragma unroll
    for (int i = 0; i < 4; i++) {
        int s = wave * 256 + i * 64 + lane;
        s_slot[i] = (wave * 256 + i * 64) * 8;
        s_row[i] = s >> 3;
        s_c16[i] = (s & 7) ^ ((s >> 3) & 7);
    }

    f32x4 acc[4][4] = {};

    for (int k0 = 0; k0 < K; k0 += BK) {
        #pragma unroll
        for (int i = 0; i < 4; i++) {
            gl_lds16(A  + (size_t)(bm + s_row[i]) * K + k0 + s_c16[i] * 8, &As[s_slot[i]]);
            gl_lds16(Bw + (size_t)(bn + s_row[i]) * K + k0 + s_c16[i] * 8, &Bs[s_slot[i]]);
        }
        __syncthreads();
        #pragma unroll
        for (int ks = 0; ks < 2; ks++) {
            bf16x8 a[4], b[4];
            #pragma unroll
            for (int mi = 0; mi < 4; mi++) {
                int row = wm + mi * 16 + fr;
                a[mi] = *(const bf16x8*)&As[row * 64 + (((ks * 4 + fg) ^ (row & 7)) << 3)];
            }
            #pragma unroll
            for (int ni = 0; ni < 4; ni++) {
                int row = wn + ni * 16 + fr;
                b[ni] = *(const bf16x8*)&Bs[row * 64 + (((ks * 4 + fg) ^ (row & 7)) << 3)];
            }
            #pragma unroll
            for (int mi = 0; mi < 4; mi++)
                #pragma unroll
                for (int ni = 0; ni < 4; ni++)
                    acc[mi][ni] = __builtin_amdgcn_mfma_f32_16x16x32_bf16(a[mi], b[ni], acc[mi][ni], 0, 0, 0);
        }
        __syncthreads();
    }

    #pragma unroll
    for (int mi = 0; mi < 4; mi++) {
        #pragma unroll
        for (int ni = 0; ni < 4; ni++) {
            int col = bn + wn + ni * 16 + fr;
            int row0 = bm + wm + mi * 16 + fg * 4;
            float bv = bias ? bias[col] : 0.0f;
            #pragma unroll
            for (int r = 0; r < 4; r++) {
                float v = acc[mi][ni][r] + bv;
                C[(size_t)(row0 + r) * N + col] = f2b(v);
            }
        }
    }
}

// ---------- fused GEMM2: C = GELU(BN(A)) @ Bw^T + bias ----------
// A (raw Yb) reg-staged with scale/shift+gelu_fast transform, ds_write into the
// SAME swizzled layout (granule ^ row&7) the MFMA reads; B stays gl_lds16.
// Segment (per-block uniform; BM=128 divides all segment boundaries).
__global__ __launch_bounds__(256, 4) void mfma_gemm_bngelu(
    const unsigned short* __restrict__ A, const unsigned short* __restrict__ Bw,
    const float* __restrict__ bias, unsigned short* __restrict__ C,
    int M, int N, int K,
    const float* __restrict__ bnscale, const float* __restrict__ bnshift)
{
    __shared__ unsigned short As[BM * BK];
    __shared__ unsigned short Bs[BN * BK];
    const int tid = threadIdx.x;
    int bxi = blockIdx.x, byi = blockIdx.y;
    xcd_swizzle(bxi, byi);
    const int bm = byi * BM;
    const int bn = bxi * BN;
    const int wave = tid >> 6;
    const int lane = tid & 63;
    const int wm = (wave >> 1) * 64;
    const int wn = (wave & 1) * 64;
    const int fr = lane & 15;
    const int fg = lane >> 4;

    // B staging geometry (gl_lds16, inverse-swizzled source)
    int s_slot[4], s_row[4], s_c16[4];
    #pragma unroll
    for (int i = 0; i < 4; i++) {
        int s = wave * 256 + i * 64 + lane;
        s_slot[i] = (wave * 256 + i * 64) * 8;
        s_row[i] = s >> 3;
        s_c16[i] = (s & 7) ^ ((s >> 3) & 7);
    }

    // A staging geometry (reg-staged transform)
    const int srow = tid >> 1;            // 0..127
    const int scol = (tid & 1) * 32;      // 0 or 32
    const int seg = (bm < BATCH) ? 0 : (bm < 2 * BATCH) ? 1 : 2;
    const float* scp = bnscale + seg * HID;
    const float* shp = bnshift + seg * HID;
    const unsigned short* arow = A + (size_t)(bm + srow) * K + scol;

    f32x4 acc[4][4] = {};

    for (int k0 = 0; k0 < K; k0 += BK) {
        // ---- stage B tile (async) ----
        #pragma unroll
        for (int i = 0; i < 4; i++) {
            gl_lds16(Bw + (size_t)(bn + s_row[i]) * K + k0 + s_c16[i] * 8, &Bs[s_slot[i]]);
        }
        // ---- stage A tile: load raw, BN+GELU, swizzled ds_write ----
        {
            union { unsigned short us[32]; uint4 u4[4]; } raw, tmp;
            const uint4* src = (const uint4*)(arow + k0);
            #pragma unroll
            for (int i = 0; i < 4; i++) raw.u4[i] = src[i];
            #pragma unroll
            for (int j = 0; j < 32; j += 4) {
                int kc = k0 + scol + j;
                float4 sc = *(const float4*)(scp + kc);
                float4 sh = *(const float4*)(shp + kc);
                tmp.us[j+0] = f2b(gelu_fast(fmaf(b2f(raw.us[j+0]), sc.x, sh.x)));
                tmp.us[j+1] = f2b(gelu_fast(fmaf(b2f(raw.us[j+1]), sc.y, sh.y)));
                tmp.us[j+2] = f2b(gelu_fast(fmaf(b2f(raw.us[j+2]), sc.z, sh.z)));
                tmp.us[j+3] = f2b(gelu_fast(fmaf(b2f(raw.us[j+3]), sc.w, sh.w)));
            }
            #pragma unroll
            for (int cidx = 0; cidx < 4; cidx++) {
                int gl = (scol >> 3) + cidx;
                *(uint4*)&As[srow * 64 + ((gl ^ (srow & 7)) << 3)] = tmp.u4[cidx];
            }
        }
        __syncthreads();
        #pragma unroll
        for (int ks = 0; ks < 2; ks++) {
            bf16x8 a[4], b[4];
            #pragma unroll
            for (int mi = 0; mi < 4; mi++) {
                int row = wm + mi * 16 + fr;
                a[mi] = *(const bf16x8*)&As[row * 64 + (((ks * 4 + fg) ^ (row & 7)) << 3)];
            }
            #pragma unroll
            for (int ni = 0; ni < 4; ni++) {
                int row = wn + ni * 16 + fr;
                b[ni] = *(const bf16x8*)&Bs[row * 64 + (((ks * 4 + fg) ^ (row & 7)) << 3)];
            }
            #pragma unroll
            for (int mi = 0; mi < 4; mi++)
                #pragma unroll
                for (int ni = 0; ni < 4; ni++)
                    acc[mi][ni] = __builtin_amdgcn_mfma_f32_16x16x32_bf16(a[mi], b[ni], acc[mi][ni], 0, 0, 0);
        }
        __syncthreads();
    }

    #pragma unroll
    for (int mi = 0; mi < 4; mi++) {
        #pragma unroll
        for (int ni = 0; ni < 4; ni++) {
            int col = bn + wn + ni * 16 + fr;
            int row0 = bm + wm + mi * 16 + fg * 4;
            float bv = bias[col];
            #pragma unroll
            for (int r = 0; r < 4; r++) {
                float v = acc[mi][ni][r] + bv;
                C[(size_t)(row0 + r) * N + col] = f2b(v);
            }
        }
    }
}

// ---------- BN stats, stage 1: per-block partials, atomic-free ----------
__global__ __launch_bounds__(256) void bn_stats_partial(const unsigned short* __restrict__ Yb,
                                                        float* __restrict__ partial)
{
    __shared__ float lsum[1024];
    __shared__ float lssq[1024];
    const int cg = (threadIdx.x & 127) * 8;
    int r = blockIdx.x * BNS_ROWS + (threadIdx.x >> 7);
    float s[8] = {}, ss[8] = {};
    #pragma unroll 4
    for (int i = 0; i < BNS_ROWS / 2; i++, r += 2) {
        uint4 v = *(const uint4*)&Yb[(size_t)r * HID + cg];
        const unsigned short* u = (const unsigned short*)&v;
        #pragma unroll
        for (int j = 0; j < 8; j++) {
            float f = b2f(u[j]);
            s[j] += f; ss[j] += f * f;
        }
    }
    if (threadIdx.x >= 128) {
        #pragma unroll
        for (int j = 0; j < 8; j++) { lsum[cg + j] = s[j]; lssq[cg + j] = ss[j]; }
    }
    __syncthreads();
    if (threadIdx.x < 128) {
        float* outs = partial + (size_t)blockIdx.x * 2048;
        #pragma unroll
        for (int j = 0; j < 8; j++) {
            outs[cg + j]        = s[j] + lsum[cg + j];
            outs[1024 + cg + j] = ss[j] + lssq[cg + j];
        }
    }
}

// ---------- BN stats, stage 2 ----------
__global__ __launch_bounds__(256) void bn_reduce_finalize(
    const float* __restrict__ partial,
    const float* __restrict__ gamma, const float* __restrict__ beta,
    float* __restrict__ scale, float* __restrict__ shift)
{
    int seg = blockIdx.y;
    int col = blockIdx.x * 256 + threadIdx.x;
    int base = (seg == 0) ? 0 : (seg == 1) ? 32 : 64;
    int nblk = (seg == 2) ? 256 : 32;
    const float* p = partial + (size_t)base * 2048;
    float s = 0.f, ss = 0.f;
    for (int b = 0; b < nblk; b++) {
        s  += p[(size_t)b * 2048 + col];
        ss += p[(size_t)b * 2048 + 1024 + col];
    }
    float n = (seg == 2) ? (float)NNEG : (float)BATCH;
    float mu = s / n;
    float var = ss / n - mu * mu;
    float sc = gamma[col] * rsqrtf(var + 1e-5f);
    scale[seg * HID + col] = sc;
    shift[seg * HID + col] = beta[col] - mu * sc;
}

// ---------- L2 normalize rows in place (bf16); fp32 copy for first 8192 rows ----------
__global__ __launch_bounds__(256) void l2norm(unsigned short* __restrict__ Z,
                                              float* __restrict__ Zfp)
{
    __shared__ float scratch[4];
    size_t r = blockIdx.x;
    float v = b2f(Z[r * PROJ + threadIdx.x]);
    float t = blockReduceSumF(v * v, scratch);
    float scale = 1.0f / fmaxf(sqrtf(t), 1e-12f);
    float o = v * scale;
    Z[r * PROJ + threadIdx.x] = f2b(o);
    if (r < 2 * BATCH) Zfp[r * PROJ + threadIdx.x] = o;
}

// ---------- two-pass hist top-k loss (R14-proven: wave-scan suffix sum) ----------
__global__ __launch_bounds__(256) void topk_loss(
    const unsigned short* __restrict__ simb,   // [CHUNK x NNEG]
    const float* __restrict__ z1, const float* __restrict__ z2,
    int rowOffset, float* __restrict__ rowloss)
{
    __shared__ int   hcnt[4096];
    __shared__ int   segc[256];
    __shared__ int   sufc[256];
    __shared__ int   wtot[4];
    __shared__ float fscratch[4];
    __shared__ int   iscratch[4];
    __shared__ int   sel_seg;
    __shared__ int   sh_bt, sh_run;

    const int tid = threadIdx.x;
    const int lane = tid & 63;
    const int wid = tid >> 6;
    const int grow = rowOffset + blockIdx.x;
    const unsigned short* srow = simb + (size_t)blockIdx.x * NNEG;

    #pragma unroll
    for (int j = 0; j < 16; j++) hcnt[tid * 16 + j] = 0;

    float p = z1[(size_t)grow * PROJ + tid] * z2[(size_t)grow * PROJ + tid];
    float pos = blockReduceSumF(p, fscratch);
    __syncthreads();

    // ---- pass 1: count histogram ----
    for (int i = tid * 8; i < NNEG; i += 256 * 8) {
        uint4 v4 = *(const uint4*)(srow + i);
        const unsigned short* u = (const unsigned short*)&v4;
        #pragma unroll
        for (int j = 0; j < 8; j++) {
            float v = b2f(u[j]);
            int k = (int)fmaf(v, 2048.f, 2048.f);
            k = min(max(k, 0), 4095);
            atomicAdd(&hcnt[k], 1);
        }
    }
    __syncthreads();

    int c = 0;
    #pragma unroll
    for (int j = 0; j < 16; j++) c += hcnt[tid * 16 + j];

    int v = c;
    #pragma unroll
    for (int o = 1; o < 64; o <<= 1) {
        int t = __shfl_down(v, o);
        if (lane + o < 64) v += t;
    }
    if (lane == 0) wtot[wid] = v;
    __syncthreads();
    int suf = v;
    #pragma unroll
    for (int w = 0; w < 4; w++) if (w > wid) suf += wtot[w];
    segc[tid] = c;
    sufc[tid] = suf;
    if (suf >= TOPK && suf - c < TOPK) sel_seg = tid;
    __syncthreads();

    if (tid == 0) {
        int t = sel_seg;
        int running = sufc[t] - segc[t];
        int bt = t * 16;
        for (int j = 15; j >= 0; j--) {
            int b = t * 16 + j;
            int cb = hcnt[b];
            if (running + cb >= TOPK) { bt = b; break; }
            running += cb;
        }
        sh_bt = bt; sh_run = running;
    }
    __syncthreads();
    const int bt = sh_bt;
    const float m = INV_T;

    // ---- pass 2: exp only above/at threshold bucket ----
    float s_above = 0.f, s_eq = 0.f;
    int c_eq = 0;
    for (int i = tid * 8; i < NNEG; i += 256 * 8) {
        uint4 v4 = *(const uint4*)(srow + i);
        const unsigned short* u = (const unsigned short*)&v4;
        #pragma unroll
        for (int j = 0; j < 8; j++) {
            float vv = b2f(u[j]);
            int k = (int)fmaf(vv, 2048.f, 2048.f);
            k = min(max(k, 0), 4095);
            if (k >= bt) {
                float e = __expf(fmaf(vv, INV_T, -m));
                if (k > bt) s_above += e;
                else { s_eq += e; c_eq++; }
            }
        }
    }
    s_above = blockReduceSumF(s_above, fscratch);
    __syncthreads();
    s_eq = blockReduceSumF(s_eq, fscratch);
    c_eq = blockReduceSumI(c_eq, iscratch);
    if (tid == 0) {
        int need = TOPK - sh_run;
        float avg = s_eq / (float)c_eq;
        float total = s_above + (float)need * avg + __expf(fmaf(pos, INV_T, -m));
        rowloss[grow] = m + logf(total) - pos * INV_T;
    }
}

__global__ __launch_bounds__(256) void loss_reduce(const float* __restrict__ rowloss,
                                                   float* __restrict__ out)
{
    __shared__ float scratch[4];
    float s = 0.f;
    for (int i = threadIdx.x; i < BATCH; i += 256) s += rowloss[i];
    s = blockReduceSumF(s, scratch);
    if (threadIdx.x == 0) out[0] = s / (float)BATCH;
}

// ---------- launcher ----------
extern "C" void kernel_launch(void* const* d_in, const int* in_sizes, int n_in,
                              void* d_out, int out_size, void* d_ws, size_t ws_size,
                              hipStream_t stream)
{
    const float* h1    = (const float*)d_in[0];
    const float* h2    = (const float*)d_in[1];
    const float* hneg  = (const float*)d_in[2];
    const float* W1    = (const float*)d_in[3];
    const float* b1    = (const float*)d_in[4];
    const float* gamma = (const float*)d_in[5];
    const float* beta  = (const float*)d_in[6];
    const float* W2    = (const float*)d_in[7];
    const float* b2    = (const float*)d_in[8];
    float* out = (float*)d_out;
    float* ws  = (float*)d_ws;

    // workspace layout (float offsets); total 50,604,032 f = 202.4 MB
    unsigned short* X_all = (unsigned short*)ws;                  // 40960x1024 bf16 = 20,971,520 f
    unsigned short* Yb    = (unsigned short*)(ws + 20971520);     // 40960x1024 bf16 = 20,971,520 f
    unsigned short* Z     = (unsigned short*)(ws + 41943040);     // 40960x256 bf16 (in-place norm)
    unsigned short* W1b   = (unsigned short*)(ws + 47185920);     // 1M bf16
    unsigned short* W2b   = (unsigned short*)(ws + 47710208);     // 256K bf16
    float* partial = ws + 47841280;                               // (32+32+256)*2048 = 655,360 f
    float* s_scale = ws + 48496640;                               // 3*1024
    float* s_shift = ws + 48499712;                               // 3*1024
    float* rowloss = ws + 48502784;                               // 4096
    float* Zfp     = ws + 48506880;                               // 8192x256 f32 = 2,097,152 f
    // overlay: simb spans X_all+Yb (both dead after GEMM2): 128 MB < 160 MB
    unsigned short* simb = X_all;

    // conversions: weights + all inputs -> bf16 (contiguous X_all = [h1; h2; hneg])
    conv_f2b<<<1024, 256, 0, stream>>>(W1, W1b, HID * HID);
    conv_f2b<<<256, 256, 0, stream>>>(W2, W2b, PROJ * HID);
    conv_f2b8<<<2048, 256, 0, stream>>>(h1, X_all);
    conv_f2b8<<<2048, 256, 0, stream>>>(h2, X_all + (size_t)BATCH * HID);
    conv_f2b8<<<16384, 256, 0, stream>>>(hneg, X_all + (size_t)2 * BATCH * HID);

    // GEMM1 (single dispatch): Yb = X_all @ W1b^T + b1
    {
        dim3 g(HID / BN, ROWS_TOTAL / BM);
        mfma_gemm<<<g, 256, 0, stream>>>(X_all, W1b, b1, Yb, ROWS_TOTAL, HID, HID);
    }

    const int rows[3] = { BATCH, BATCH, NNEG };
    const int yoff[3] = { 0, BATCH, 2 * BATCH };
    const int poff[3] = { 0, 32, 64 };

    // BN stats: atomic-free partials + fused reduce/finalize (on RAW Yb)
    for (int s = 0; s < 3; s++) {
        bn_stats_partial<<<rows[s] / BNS_ROWS, 256, 0, stream>>>(
            Yb + (size_t)yoff[s] * HID, partial + (size_t)poff[s] * 2048);
    }
    bn_reduce_finalize<<<dim3(HID / 256, 3), 256, 0, stream>>>(partial, gamma, beta, s_scale, s_shift);

    // GEMM2 fused: Z = GELU(BN(Yb)) @ W2b^T + b2  (bngelu pass deleted)
    {
        dim3 g(PROJ / BN, ROWS_TOTAL / BM);
        mfma_gemm_bngelu<<<g, 256, 0, stream>>>(Yb, W2b, b2, Z, ROWS_TOTAL, PROJ, HID,
                                                s_scale, s_shift);
    }
    // L2 normalize in place; fp32 copy of z1/z2
    l2norm<<<ROWS_TOTAL, 256, 0, stream>>>(Z, Zfp);

    // sim chunks (2 x 2048 rows): sim = z1_chunk @ z_neg^T, then two-pass topk loss
    const unsigned short* znegb = Z + (size_t)(2 * BATCH) * PROJ;
    const float* z2v = Zfp + (size_t)BATCH * PROJ;
    for (int c = 0; c < BATCH / CHUNK; c++) {
        dim3 g(NNEG / BN, CHUNK / BM);
        mfma_gemm<<<g, 256, 0, stream>>>(Z + (size_t)(c * CHUNK) * PROJ, znegb, nullptr,
                                         simb, CHUNK, NNEG, PROJ);
        topk_loss<<<CHUNK, 256, 0, stream>>>(simb, Zfp, z2v, c * CHUNK, rowloss);
    }
    loss_reduce<<<1, 256, 0, stream>>>(rowloss, out);
}

// Round 21
// 530.308 us; speedup vs baseline: 1.1415x; 1.1415x over previous
//
#include <hip/hip_runtime.h>
#include <hip/hip_bf16.h>
#include <math.h>

#define BATCH 4096
#define NNEG 32768
#define HID 1024
#define PROJ 256
#define TOPK 128
#define ROWS_TOTAL 40960
#define CHUNK 2048
#define INV_T 14.2857142857142857f  // 1/0.07

#define BM 128
#define BN 128
#define BK 64

#define BNS_ROWS 128   // rows per bn_stats_partial block

typedef __attribute__((ext_vector_type(8))) short bf16x8;
typedef __attribute__((ext_vector_type(4))) float f32x4;

// ---------- helpers ----------
__device__ __forceinline__ float b2f(unsigned short u) {
    return __uint_as_float(((unsigned)u) << 16);
}
__device__ __forceinline__ unsigned short f2b(float f) {
    unsigned u = __float_as_uint(f);
    unsigned r = (u + 0x7FFFu + ((u >> 16) & 1u)) >> 16;  // RNE
    return (unsigned short)r;
}
// branchless tanh-GELU, exp2 form
__device__ __forceinline__ float gelu_fast(float v) {
    float v2 = v * v;
    float w = v * fmaf(v2, -0.1029433f, -2.3022086f);
    float e = exp2f(w);
    return v * __builtin_amdgcn_rcpf(1.0f + e);
}

__device__ __forceinline__ float blockReduceSumF(float v, volatile float* scratch) {
    #pragma unroll
    for (int o = 32; o > 0; o >>= 1) v += __shfl_down(v, o);
    int wid = threadIdx.x >> 6, lane = threadIdx.x & 63;
    __syncthreads();
    if (lane == 0) scratch[wid] = v;
    __syncthreads();
    return scratch[0] + scratch[1] + scratch[2] + scratch[3];
}
__device__ __forceinline__ int blockReduceSumI(int v, volatile int* scratch) {
    #pragma unroll
    for (int o = 32; o > 0; o >>= 1) v += __shfl_down(v, o);
    int wid = threadIdx.x >> 6, lane = threadIdx.x & 63;
    __syncthreads();
    if (lane == 0) scratch[wid] = v;
    __syncthreads();
    return scratch[0] + scratch[1] + scratch[2] + scratch[3];
}

// async global->LDS, 16B per lane; lds base must be wave-uniform
__device__ __forceinline__ void gl_lds16(const unsigned short* g, unsigned short* l) {
    __builtin_amdgcn_global_load_lds(
        (const __attribute__((address_space(1))) unsigned*)g,
        (__attribute__((address_space(3))) unsigned*)l, 16, 0, 0);
}

// ---------- fp32 -> bf16 conversion ----------
__global__ __launch_bounds__(256) void conv_f2b(const float* __restrict__ src,
                                                unsigned short* __restrict__ dst, int n)
{
    int i = (blockIdx.x * 256 + threadIdx.x) * 4;
    if (i + 3 < n) {
        float4 v = *(const float4*)(src + i);
        ushort4 o;
        o.x = f2b(v.x); o.y = f2b(v.y); o.z = f2b(v.z); o.w = f2b(v.w);
        *(ushort4*)(dst + i) = o;
    }
}

__global__ __launch_bounds__(256) void conv_f2b8(const float* __restrict__ src,
                                                 unsigned short* __restrict__ dst)
{
    int i = (blockIdx.x * 256 + threadIdx.x) * 8;
    float4 a = *(const float4*)(src + i);
    float4 b = *(const float4*)(src + i + 4);
    ushort4 o0, o1;
    o0.x = f2b(a.x); o0.y = f2b(a.y); o0.z = f2b(a.z); o0.w = f2b(a.w);
    o1.x = f2b(b.x); o1.y = f2b(b.y); o1.z = f2b(b.z); o1.w = f2b(b.w);
    *(ushort4*)(dst + i) = o0;
    *(ushort4*)(dst + i + 4) = o1;
}

// ---------- XCD-chunked bijective swizzle (nwg % 8 == 0 in all launches) ----------
__device__ __forceinline__ void xcd_swizzle(int& bx, int& by) {
    int gx = gridDim.x;
    int orig = by * gx + bx;
    int q = (gx * gridDim.y) >> 3;
    int wg = (orig & 7) * q + (orig >> 3);
    bx = wg % gx;
    by = wg / gx;
}

// ---------- MFMA GEMM (R17/R19-proven: single-buffer BK=64, 4 waves/SIMD) ----------
__global__ __launch_bounds__(256, 4) void mfma_gemm(
    const unsigned short* __restrict__ A, const unsigned short* __restrict__ Bw,
    const float* __restrict__ bias, unsigned short* __restrict__ C,
    int M, int N, int K)
{
    __shared__ unsigned short As[BM * BK];
    __shared__ unsigned short Bs[BN * BK];
    const int tid = threadIdx.x;
    int bxi = blockIdx.x, byi = blockIdx.y;
    xcd_swizzle(bxi, byi);
    const int bm = byi * BM;
    const int bn = bxi * BN;
    const int wave = tid >> 6;
    const int lane = tid & 63;
    const int wm = (wave >> 1) * 64;
    const int wn = (wave & 1) * 64;
    const int fr = lane & 15;
    const int fg = lane >> 4;

    int s_slot[4], s_row[4], s_c16[4];
    #pragma unroll
    for (int i = 0; i < 4; i++) {
        int s = wave * 256 + i * 64 + lane;
        s_slot[i] = (wave * 256 + i * 64) * 8;
        s_row[i] = s >> 3;
        s_c16[i] = (s & 7) ^ ((s >> 3) & 7);
    }

    f32x4 acc[4][4] = {};

    for (int k0 = 0; k0 < K; k0 += BK) {
        #pragma unroll
        for (int i = 0; i < 4; i++) {
            gl_lds16(A  + (size_t)(bm + s_row[i]) * K + k0 + s_c16[i] * 8, &As[s_slot[i]]);
            gl_lds16(Bw + (size_t)(bn + s_row[i]) * K + k0 + s_c16[i] * 8, &Bs[s_slot[i]]);
        }
        __syncthreads();
        #pragma unroll
        for (int ks = 0; ks < 2; ks++) {
            bf16x8 a[4], b[4];
            #pragma unroll
            for (int mi = 0; mi < 4; mi++) {
                int row = wm + mi * 16 + fr;
                a[mi] = *(const bf16x8*)&As[row * 64 + (((ks * 4 + fg) ^ (row & 7)) << 3)];
            }
            #pragma unroll
            for (int ni = 0; ni < 4; ni++) {
                int row = wn + ni * 16 + fr;
                b[ni] = *(const bf16x8*)&Bs[row * 64 + (((ks * 4 + fg) ^ (row & 7)) << 3)];
            }
            #pragma unroll
            for (int mi = 0; mi < 4; mi++)
                #pragma unroll
                for (int ni = 0; ni < 4; ni++)
                    acc[mi][ni] = __builtin_amdgcn_mfma_f32_16x16x32_bf16(a[mi], b[ni], acc[mi][ni], 0, 0, 0);
        }
        __syncthreads();
    }

    #pragma unroll
    for (int mi = 0; mi < 4; mi++) {
        #pragma unroll
        for (int ni = 0; ni < 4; ni++) {
            int col = bn + wn + ni * 16 + fr;
            int row0 = bm + wm + mi * 16 + fg * 4;
            float bv = bias ? bias[col] : 0.0f;
            #pragma unroll
            for (int r = 0; r < 4; r++) {
                float v = acc[mi][ni][r] + bv;
                C[(size_t)(row0 + r) * N + col] = f2b(v);
            }
        }
    }
}

// ---------- BN stats, stage 1: single dispatch over all rows, atomic-free ----------
// Block b reads Yb rows [128b, 128b+128); partial slot = b. Segment boundaries
// (4096/8192) align to block 32/64, matching bn_reduce_finalize's layout.
__global__ __launch_bounds__(256) void bn_stats_partial(const unsigned short* __restrict__ Yb,
                                                        float* __restrict__ partial)
{
    __shared__ float lsum[1024];
    __shared__ float lssq[1024];
    const int cg = (threadIdx.x & 127) * 8;
    int r = blockIdx.x * BNS_ROWS + (threadIdx.x >> 7);
    float s[8] = {}, ss[8] = {};
    #pragma unroll 4
    for (int i = 0; i < BNS_ROWS / 2; i++, r += 2) {
        uint4 v = *(const uint4*)&Yb[(size_t)r * HID + cg];
        const unsigned short* u = (const unsigned short*)&v;
        #pragma unroll
        for (int j = 0; j < 8; j++) {
            float f = b2f(u[j]);
            s[j] += f; ss[j] += f * f;
        }
    }
    if (threadIdx.x >= 128) {
        #pragma unroll
        for (int j = 0; j < 8; j++) { lsum[cg + j] = s[j]; lssq[cg + j] = ss[j]; }
    }
    __syncthreads();
    if (threadIdx.x < 128) {
        float* outs = partial + (size_t)blockIdx.x * 2048;
        #pragma unroll
        for (int j = 0; j < 8; j++) {
            outs[cg + j]        = s[j] + lsum[cg + j];
            outs[1024 + cg + j] = ss[j] + lssq[cg + j];
        }
    }
}

// ---------- BN stats, stage 2 ----------
__global__ __launch_bounds__(256) void bn_reduce_finalize(
    const float* __restrict__ partial,
    const float* __restrict__ gamma, const float* __restrict__ beta,
    float* __restrict__ scale, float* __restrict__ shift)
{
    int seg = blockIdx.y;
    int col = blockIdx.x * 256 + threadIdx.x;
    int base = (seg == 0) ? 0 : (seg == 1) ? 32 : 64;
    int nblk = (seg == 2) ? 256 : 32;
    const float* p = partial + (size_t)base * 2048;
    float s = 0.f, ss = 0.f;
    for (int b = 0; b < nblk; b++) {
        s  += p[(size_t)b * 2048 + col];
        ss += p[(size_t)b * 2048 + 1024 + col];
    }
    float n = (seg == 2) ? (float)NNEG : (float)BATCH;
    float mu = s / n;
    float var = ss / n - mu * mu;
    float sc = gamma[col] * rsqrtf(var + 1e-5f);
    scale[seg * HID + col] = sc;
    shift[seg * HID + col] = beta[col] - mu * sc;
}

// ---------- in-place BN + fast GELU over Yb (8 elems/thread) ----------
__global__ __launch_bounds__(256) void bngelu(unsigned short* __restrict__ Yb,
                                              const float* __restrict__ scale,
                                              const float* __restrict__ shift)
{
    size_t i = ((size_t)blockIdx.x * 256 + threadIdx.x) * 8;
    int row = (int)(i >> 10);
    int seg = (row < BATCH) ? 0 : (row < 2 * BATCH) ? 1 : 2;
    int col = (int)(i & 1023);
    float4 sc0 = *(const float4*)(scale + seg * HID + col);
    float4 sc1 = *(const float4*)(scale + seg * HID + col + 4);
    float4 sh0 = *(const float4*)(shift + seg * HID + col);
    float4 sh1 = *(const float4*)(shift + seg * HID + col + 4);
    float sc[8] = { sc0.x, sc0.y, sc0.z, sc0.w, sc1.x, sc1.y, sc1.z, sc1.w };
    float sh[8] = { sh0.x, sh0.y, sh0.z, sh0.w, sh1.x, sh1.y, sh1.z, sh1.w };
    uint4 v = *(uint4*)&Yb[i];
    unsigned short* u = (unsigned short*)&v;
    #pragma unroll
    for (int j = 0; j < 8; j++) {
        float f = fmaf(b2f(u[j]), sc[j], sh[j]);
        u[j] = f2b(gelu_fast(f));
    }
    *(uint4*)&Yb[i] = v;
}

// ---------- L2 normalize rows in place (bf16); fp32 copy for first 8192 rows ----------
__global__ __launch_bounds__(256) void l2norm(unsigned short* __restrict__ Z,
                                              float* __restrict__ Zfp)
{
    __shared__ float scratch[4];
    size_t r = blockIdx.x;
    float v = b2f(Z[r * PROJ + threadIdx.x]);
    float t = blockReduceSumF(v * v, scratch);
    float scale = 1.0f / fmaxf(sqrtf(t), 1e-12f);
    float o = v * scale;
    Z[r * PROJ + threadIdx.x] = f2b(o);
    if (r < 2 * BATCH) Zfp[r * PROJ + threadIdx.x] = o;
}

// ---------- two-pass hist top-k loss (R14-proven: wave-scan suffix sum) ----------
__global__ __launch_bounds__(256) void topk_loss(
    const unsigned short* __restrict__ simb,   // [CHUNK x NNEG]
    const float* __restrict__ z1, const float* __restrict__ z2,
    int rowOffset, float* __restrict__ rowloss)
{
    __shared__ int   hcnt[4096];
    __shared__ int   segc[256];
    __shared__ int   sufc[256];
    __shared__ int   wtot[4];
    __shared__ float fscratch[4];
    __shared__ int   iscratch[4];
    __shared__ int   sel_seg;
    __shared__ int   sh_bt, sh_run;

    const int tid = threadIdx.x;
    const int lane = tid & 63;
    const int wid = tid >> 6;
    const int grow = rowOffset + blockIdx.x;
    const unsigned short* srow = simb + (size_t)blockIdx.x * NNEG;

    #pragma unroll
    for (int j = 0; j < 16; j++) hcnt[tid * 16 + j] = 0;

    float p = z1[(size_t)grow * PROJ + tid] * z2[(size_t)grow * PROJ + tid];
    float pos = blockReduceSumF(p, fscratch);
    __syncthreads();

    // ---- pass 1: count histogram ----
    for (int i = tid * 8; i < NNEG; i += 256 * 8) {
        uint4 v4 = *(const uint4*)(srow + i);
        const unsigned short* u = (const unsigned short*)&v4;
        #pragma unroll
        for (int j = 0; j < 8; j++) {
            float v = b2f(u[j]);
            int k = (int)fmaf(v, 2048.f, 2048.f);
            k = min(max(k, 0), 4095);
            atomicAdd(&hcnt[k], 1);
        }
    }
    __syncthreads();

    int c = 0;
    #pragma unroll
    for (int j = 0; j < 16; j++) c += hcnt[tid * 16 + j];

    int v = c;
    #pragma unroll
    for (int o = 1; o < 64; o <<= 1) {
        int t = __shfl_down(v, o);
        if (lane + o < 64) v += t;
    }
    if (lane == 0) wtot[wid] = v;
    __syncthreads();
    int suf = v;
    #pragma unroll
    for (int w = 0; w < 4; w++) if (w > wid) suf += wtot[w];
    segc[tid] = c;
    sufc[tid] = suf;
    if (suf >= TOPK && suf - c < TOPK) sel_seg = tid;
    __syncthreads();

    if (tid == 0) {
        int t = sel_seg;
        int running = sufc[t] - segc[t];
        int bt = t * 16;
        for (int j = 15; j >= 0; j--) {
            int b = t * 16 + j;
            int cb = hcnt[b];
            if (running + cb >= TOPK) { bt = b; break; }
            running += cb;
        }
        sh_bt = bt; sh_run = running;
    }
    __syncthreads();
    const int bt = sh_bt;
    const float m = INV_T;

    // ---- pass 2: exp only above/at threshold bucket ----
    float s_above = 0.f, s_eq = 0.f;
    int c_eq = 0;
    for (int i = tid * 8; i < NNEG; i += 256 * 8) {
        uint4 v4 = *(const uint4*)(srow + i);
        const unsigned short* u = (const unsigned short*)&v4;
        #pragma unroll
        for (int j = 0; j < 8; j++) {
            float vv = b2f(u[j]);
            int k = (int)fmaf(vv, 2048.f, 2048.f);
            k = min(max(k, 0), 4095);
            if (k >= bt) {
                float e = __expf(fmaf(vv, INV_T, -m));
                if (k > bt) s_above += e;
                else { s_eq += e; c_eq++; }
            }
        }
    }
    s_above = blockReduceSumF(s_above, fscratch);
    __syncthreads();
    s_eq = blockReduceSumF(s_eq, fscratch);
    c_eq = blockReduceSumI(c_eq, iscratch);
    if (tid == 0) {
        int need = TOPK - sh_run;
        float avg = s_eq / (float)c_eq;
        float total = s_above + (float)need * avg + __expf(fmaf(pos, INV_T, -m));
        rowloss[grow] = m + logf(total) - pos * INV_T;
    }
}

__global__ __launch_bounds__(256) void loss_reduce(const float* __restrict__ rowloss,
                                                   float* __restrict__ out)
{
    __shared__ float scratch[4];
    float s = 0.f;
    for (int i = threadIdx.x; i < BATCH; i += 256) s += rowloss[i];
    s = blockReduceSumF(s, scratch);
    if (threadIdx.x == 0) out[0] = s / (float)BATCH;
}

// ---------- launcher ----------
extern "C" void kernel_launch(void* const* d_in, const int* in_sizes, int n_in,
                              void* d_out, int out_size, void* d_ws, size_t ws_size,
                              hipStream_t stream)
{
    const float* h1    = (const float*)d_in[0];
    const float* h2    = (const float*)d_in[1];
    const float* hneg  = (const float*)d_in[2];
    const float* W1    = (const float*)d_in[3];
    const float* b1    = (const float*)d_in[4];
    const float* gamma = (const float*)d_in[5];
    const float* beta  = (const float*)d_in[6];
    const float* W2    = (const float*)d_in[7];
    const float* b2    = (const float*)d_in[8];
    float* out = (float*)d_out;
    float* ws  = (float*)d_ws;

    // workspace layout (float offsets); total 50,604,032 f = 202.4 MB
    unsigned short* X_all = (unsigned short*)ws;                  // 40960x1024 bf16 = 20,971,520 f
    unsigned short* Yb    = (unsigned short*)(ws + 20971520);     // 40960x1024 bf16 = 20,971,520 f
    unsigned short* Z     = (unsigned short*)(ws + 41943040);     // 40960x256 bf16 (in-place norm)
    unsigned short* W1b   = (unsigned short*)(ws + 47185920);     // 1M bf16
    unsigned short* W2b   = (unsigned short*)(ws + 47710208);     // 256K bf16
    float* partial = ws + 47841280;                               // 320*2048 = 655,360 f
    float* s_scale = ws + 48496640;                               // 3*1024
    float* s_shift = ws + 48499712;                               // 3*1024
    float* rowloss = ws + 48502784;                               // 4096
    float* Zfp     = ws + 48506880;                               // 8192x256 f32 = 2,097,152 f
    // overlay: simb spans X_all+Yb (both dead after GEMM2): 128 MB < 160 MB
    unsigned short* simb = X_all;

    // conversions: weights + all inputs -> bf16 (contiguous X_all = [h1; h2; hneg])
    conv_f2b<<<1024, 256, 0, stream>>>(W1, W1b, HID * HID);
    conv_f2b<<<256, 256, 0, stream>>>(W2, W2b, PROJ * HID);
    conv_f2b8<<<2048, 256, 0, stream>>>(h1, X_all);
    conv_f2b8<<<2048, 256, 0, stream>>>(h2, X_all + (size_t)BATCH * HID);
    conv_f2b8<<<16384, 256, 0, stream>>>(hneg, X_all + (size_t)2 * BATCH * HID);

    // GEMM1 (single dispatch): Yb = X_all @ W1b^T + b1
    {
        dim3 g(HID / BN, ROWS_TOTAL / BM);
        mfma_gemm<<<g, 256, 0, stream>>>(X_all, W1b, b1, Yb, ROWS_TOTAL, HID, HID);
    }

    // BN stats: single dispatch over all 320 row-blocks (layout matches reduce)
    bn_stats_partial<<<ROWS_TOTAL / BNS_ROWS, 256, 0, stream>>>(Yb, partial);
    bn_reduce_finalize<<<dim3(HID / 256, 3), 256, 0, stream>>>(partial, gamma, beta, s_scale, s_shift);

    // in-place BN + fast GELU on Yb
    bngelu<<<ROWS_TOTAL * HID / 8 / 256, 256, 0, stream>>>(Yb, s_scale, s_shift);

    // GEMM2 (single dispatch): Z = Yb @ W2b^T + b2
    {
        dim3 g(PROJ / BN, ROWS_TOTAL / BM);
        mfma_gemm<<<g, 256, 0, stream>>>(Yb, W2b, b2, Z, ROWS_TOTAL, PROJ, HID);
    }
    // L2 normalize in place; fp32 copy of z1/z2
    l2norm<<<ROWS_TOTAL, 256, 0, stream>>>(Z, Zfp);

    // sim chunks (2 x 2048 rows): sim = z1_chunk @ z_neg^T, then two-pass topk loss
    const unsigned short* znegb = Z + (size_t)(2 * BATCH) * PROJ;
    const float* z2v = Zfp + (size_t)BATCH * PROJ;
    for (int c = 0; c < BATCH / CHUNK; c++) {
        dim3 g(NNEG / BN, CHUNK / BM);
        mfma_gemm<<<g, 256, 0, stream>>>(Z + (size_t)(c * CHUNK) * PROJ, znegb, nullptr,
                                         simb, CHUNK, NNEG, PROJ);
        topk_loss<<<CHUNK, 256, 0, stream>>>(simb, Zfp, z2v, c * CHUNK, rowloss);
    }
    loss_reduce<<<1, 256, 0, stream>>>(rowloss, out);
}

// Round 22
// 513.632 us; speedup vs baseline: 1.1786x; 1.0325x over previous
//
#include <hip/hip_runtime.h>
#include <hip/hip_bf16.h>
#include <math.h>

#define BATCH 4096
#define NNEG 32768
#define HID 1024
#define PROJ 256
#define TOPK 128
#define ROWS_TOTAL 40960
#define CHUNK 2048
#define INV_T 14.2857142857142857f  // 1/0.07

#define BM 128
#define BN 128
#define BK 64

#define BNS_ROWS 128   // rows per bn_stats_partial block

typedef __attribute__((ext_vector_type(8))) short bf16x8;
typedef __attribute__((ext_vector_type(4))) float f32x4;

// ---------- helpers ----------
__device__ __forceinline__ float b2f(unsigned short u) {
    return __uint_as_float(((unsigned)u) << 16);
}
__device__ __forceinline__ unsigned short f2b(float f) {
    unsigned u = __float_as_uint(f);
    unsigned r = (u + 0x7FFFu + ((u >> 16) & 1u)) >> 16;  // RNE
    return (unsigned short)r;
}
// branchless tanh-GELU, exp2 form
__device__ __forceinline__ float gelu_fast(float v) {
    float v2 = v * v;
    float w = v * fmaf(v2, -0.1029433f, -2.3022086f);
    float e = exp2f(w);
    return v * __builtin_amdgcn_rcpf(1.0f + e);
}

__device__ __forceinline__ float blockReduceSumF(float v, volatile float* scratch) {
    #pragma unroll
    for (int o = 32; o > 0; o >>= 1) v += __shfl_down(v, o);
    int wid = threadIdx.x >> 6, lane = threadIdx.x & 63;
    __syncthreads();
    if (lane == 0) scratch[wid] = v;
    __syncthreads();
    return scratch[0] + scratch[1] + scratch[2] + scratch[3];
}
__device__ __forceinline__ int blockReduceSumI(int v, volatile int* scratch) {
    #pragma unroll
    for (int o = 32; o > 0; o >>= 1) v += __shfl_down(v, o);
    int wid = threadIdx.x >> 6, lane = threadIdx.x & 63;
    __syncthreads();
    if (lane == 0) scratch[wid] = v;
    __syncthreads();
    return scratch[0] + scratch[1] + scratch[2] + scratch[3];
}

// async global->LDS, 16B per lane; lds base must be wave-uniform
__device__ __forceinline__ void gl_lds16(const unsigned short* g, unsigned short* l) {
    __builtin_amdgcn_global_load_lds(
        (const __attribute__((address_space(1))) unsigned*)g,
        (__attribute__((address_space(3))) unsigned*)l, 16, 0, 0);
}

// ---------- fp32 -> bf16 conversions (pair variants: block-uniform src select) ----------
// 4 elems/thread; elems [0, half) from a, rest from b. half must be a multiple
// of 1024 so the branch is block-uniform.
__global__ __launch_bounds__(256) void conv_f2b_pair(const float* __restrict__ a,
                                                     const float* __restrict__ b,
                                                     unsigned short* __restrict__ dst,
                                                     int half, int total)
{
    int i = (blockIdx.x * 256 + threadIdx.x) * 4;
    if (i >= total) return;
    const float* src = (i < half) ? (a + i) : (b + (i - half));
    float4 v = *(const float4*)src;
    ushort4 o;
    o.x = f2b(v.x); o.y = f2b(v.y); o.z = f2b(v.z); o.w = f2b(v.w);
    *(ushort4*)(dst + i) = o;
}

// 8 elems/thread; same pair logic (half multiple of 2048)
__global__ __launch_bounds__(256) void conv_f2b8_pair(const float* __restrict__ a,
                                                      const float* __restrict__ b,
                                                      unsigned short* __restrict__ dst,
                                                      int half)
{
    int i = (blockIdx.x * 256 + threadIdx.x) * 8;
    const float* src = (i < half) ? (a + i) : (b + (i - half));
    float4 x = *(const float4*)src;
    float4 y = *(const float4*)(src + 4);
    ushort4 o0, o1;
    o0.x = f2b(x.x); o0.y = f2b(x.y); o0.z = f2b(x.z); o0.w = f2b(x.w);
    o1.x = f2b(y.x); o1.y = f2b(y.y); o1.z = f2b(y.z); o1.w = f2b(y.w);
    *(ushort4*)(dst + i) = o0;
    *(ushort4*)(dst + i + 4) = o1;
}

// 8 elems/thread single-source (h_neg)
__global__ __launch_bounds__(256) void conv_f2b8(const float* __restrict__ src,
                                                 unsigned short* __restrict__ dst)
{
    int i = (blockIdx.x * 256 + threadIdx.x) * 8;
    float4 a = *(const float4*)(src + i);
    float4 b = *(const float4*)(src + i + 4);
    ushort4 o0, o1;
    o0.x = f2b(a.x); o0.y = f2b(a.y); o0.z = f2b(a.z); o0.w = f2b(a.w);
    o1.x = f2b(b.x); o1.y = f2b(b.y); o1.z = f2b(b.z); o1.w = f2b(b.w);
    *(ushort4*)(dst + i) = o0;
    *(ushort4*)(dst + i + 4) = o1;
}

// ---------- XCD-chunked bijective swizzle (nwg % 8 == 0 in all launches) ----------
__device__ __forceinline__ void xcd_swizzle(int& bx, int& by) {
    int gx = gridDim.x;
    int orig = by * gx + bx;
    int q = (gx * gridDim.y) >> 3;
    int wg = (orig & 7) * q + (orig >> 3);
    bx = wg % gx;
    by = wg / gx;
}

// ---------- MFMA GEMM (R17/R19-proven: single-buffer BK=64, 4 waves/SIMD) ----------
__global__ __launch_bounds__(256, 4) void mfma_gemm(
    const unsigned short* __restrict__ A, const unsigned short* __restrict__ Bw,
    const float* __restrict__ bias, unsigned short* __restrict__ C,
    int M, int N, int K)
{
    __shared__ unsigned short As[BM * BK];
    __shared__ unsigned short Bs[BN * BK];
    const int tid = threadIdx.x;
    int bxi = blockIdx.x, byi = blockIdx.y;
    xcd_swizzle(bxi, byi);
    const int bm = byi * BM;
    const int bn = bxi * BN;
    const int wave = tid >> 6;
    const int lane = tid & 63;
    const int wm = (wave >> 1) * 64;
    const int wn = (wave & 1) * 64;
    const int fr = lane & 15;
    const int fg = lane >> 4;

    int s_slot[4], s_row[4], s_c16[4];
    #pragma unroll
    for (int i = 0; i < 4; i++) {
        int s = wave * 256 + i * 64 + lane;
        s_slot[i] = (wave * 256 + i * 64) * 8;
        s_row[i] = s >> 3;
        s_c16[i] = (s & 7) ^ ((s >> 3) & 7);
    }

    f32x4 acc[4][4] = {};

    for (int k0 = 0; k0 < K; k0 += BK) {
        #pragma unroll
        for (int i = 0; i < 4; i++) {
            gl_lds16(A  + (size_t)(bm + s_row[i]) * K + k0 + s_c16[i] * 8, &As[s_slot[i]]);
            gl_lds16(Bw + (size_t)(bn + s_row[i]) * K + k0 + s_c16[i] * 8, &Bs[s_slot[i]]);
        }
        __syncthreads();
        #pragma unroll
        for (int ks = 0; ks < 2; ks++) {
            bf16x8 a[4], b[4];
            #pragma unroll
            for (int mi = 0; mi < 4; mi++) {
                int row = wm + mi * 16 + fr;
                a[mi] = *(const bf16x8*)&As[row * 64 + (((ks * 4 + fg) ^ (row & 7)) << 3)];
            }
            #pragma unroll
            for (int ni = 0; ni < 4; ni++) {
                int row = wn + ni * 16 + fr;
                b[ni] = *(const bf16x8*)&Bs[row * 64 + (((ks * 4 + fg) ^ (row & 7)) << 3)];
            }
            #pragma unroll
            for (int mi = 0; mi < 4; mi++)
                #pragma unroll
                for (int ni = 0; ni < 4; ni++)
                    acc[mi][ni] = __builtin_amdgcn_mfma_f32_16x16x32_bf16(a[mi], b[ni], acc[mi][ni], 0, 0, 0);
        }
        __syncthreads();
    }

    #pragma unroll
    for (int mi = 0; mi < 4; mi++) {
        #pragma unroll
        for (int ni = 0; ni < 4; ni++) {
            int col = bn + wn + ni * 16 + fr;
            int row0 = bm + wm + mi * 16 + fg * 4;
            float bv = bias ? bias[col] : 0.0f;
            #pragma unroll
            for (int r = 0; r < 4; r++) {
                float v = acc[mi][ni][r] + bv;
                C[(size_t)(row0 + r) * N + col] = f2b(v);
            }
        }
    }
}

// ---------- BN stats, stage 1: single dispatch over all rows, atomic-free ----------
__global__ __launch_bounds__(256) void bn_stats_partial(const unsigned short* __restrict__ Yb,
                                                        float* __restrict__ partial)
{
    __shared__ float lsum[1024];
    __shared__ float lssq[1024];
    const int cg = (threadIdx.x & 127) * 8;
    int r = blockIdx.x * BNS_ROWS + (threadIdx.x >> 7);
    float s[8] = {}, ss[8] = {};
    #pragma unroll 4
    for (int i = 0; i < BNS_ROWS / 2; i++, r += 2) {
        uint4 v = *(const uint4*)&Yb[(size_t)r * HID + cg];
        const unsigned short* u = (const unsigned short*)&v;
        #pragma unroll
        for (int j = 0; j < 8; j++) {
            float f = b2f(u[j]);
            s[j] += f; ss[j] += f * f;
        }
    }
    if (threadIdx.x >= 128) {
        #pragma unroll
        for (int j = 0; j < 8; j++) { lsum[cg + j] = s[j]; lssq[cg + j] = ss[j]; }
    }
    __syncthreads();
    if (threadIdx.x < 128) {
        float* outs = partial + (size_t)blockIdx.x * 2048;
        #pragma unroll
        for (int j = 0; j < 8; j++) {
            outs[cg + j]        = s[j] + lsum[cg + j];
            outs[1024 + cg + j] = ss[j] + lssq[cg + j];
        }
    }
}

// ---------- BN stats, stage 2 ----------
__global__ __launch_bounds__(256) void bn_reduce_finalize(
    const float* __restrict__ partial,
    const float* __restrict__ gamma, const float* __restrict__ beta,
    float* __restrict__ scale, float* __restrict__ shift)
{
    int seg = blockIdx.y;
    int col = blockIdx.x * 256 + threadIdx.x;
    int base = (seg == 0) ? 0 : (seg == 1) ? 32 : 64;
    int nblk = (seg == 2) ? 256 : 32;
    const float* p = partial + (size_t)base * 2048;
    float s = 0.f, ss = 0.f;
    for (int b = 0; b < nblk; b++) {
        s  += p[(size_t)b * 2048 + col];
        ss += p[(size_t)b * 2048 + 1024 + col];
    }
    float n = (seg == 2) ? (float)NNEG : (float)BATCH;
    float mu = s / n;
    float var = ss / n - mu * mu;
    float sc = gamma[col] * rsqrtf(var + 1e-5f);
    scale[seg * HID + col] = sc;
    shift[seg * HID + col] = beta[col] - mu * sc;
}

// ---------- in-place BN + fast GELU over Yb (8 elems/thread) ----------
__global__ __launch_bounds__(256) void bngelu(unsigned short* __restrict__ Yb,
                                              const float* __restrict__ scale,
                                              const float* __restrict__ shift)
{
    size_t i = ((size_t)blockIdx.x * 256 + threadIdx.x) * 8;
    int row = (int)(i >> 10);
    int seg = (row < BATCH) ? 0 : (row < 2 * BATCH) ? 1 : 2;
    int col = (int)(i & 1023);
    float4 sc0 = *(const float4*)(scale + seg * HID + col);
    float4 sc1 = *(const float4*)(scale + seg * HID + col + 4);
    float4 sh0 = *(const float4*)(shift + seg * HID + col);
    float4 sh1 = *(const float4*)(shift + seg * HID + col + 4);
    float sc[8] = { sc0.x, sc0.y, sc0.z, sc0.w, sc1.x, sc1.y, sc1.z, sc1.w };
    float sh[8] = { sh0.x, sh0.y, sh0.z, sh0.w, sh1.x, sh1.y, sh1.z, sh1.w };
    uint4 v = *(uint4*)&Yb[i];
    unsigned short* u = (unsigned short*)&v;
    #pragma unroll
    for (int j = 0; j < 8; j++) {
        float f = fmaf(b2f(u[j]), sc[j], sh[j]);
        u[j] = f2b(gelu_fast(f));
    }
    *(uint4*)&Yb[i] = v;
}

// ---------- L2 normalize: wave-per-row (4 rows/block, no barriers) ----------
__global__ __launch_bounds__(256) void l2norm(unsigned short* __restrict__ Z,
                                              float* __restrict__ Zfp)
{
    const int lane = threadIdx.x & 63;
    const int w = threadIdx.x >> 6;
    size_t r = (size_t)blockIdx.x * 4 + w;
    unsigned short* zr = Z + r * PROJ + lane * 4;
    uint2 v2 = *(uint2*)zr;
    unsigned short* u = (unsigned short*)&v2;
    float f0 = b2f(u[0]), f1 = b2f(u[1]), f2 = b2f(u[2]), f3 = b2f(u[3]);
    float t = f0 * f0 + f1 * f1 + f2 * f2 + f3 * f3;
    #pragma unroll
    for (int o = 32; o > 0; o >>= 1) t += __shfl_down(t, o);
    t = __shfl(t, 0);
    float scale = 1.0f / fmaxf(sqrtf(t), 1e-12f);
    f0 *= scale; f1 *= scale; f2 *= scale; f3 *= scale;
    u[0] = f2b(f0); u[1] = f2b(f1); u[2] = f2b(f2); u[3] = f2b(f3);
    *(uint2*)zr = v2;
    if (r < 2 * BATCH) {
        float4 o4 = { f0, f1, f2, f3 };
        *(float4*)(Zfp + r * PROJ + lane * 4) = o4;
    }
}

// ---------- two-pass hist top-k loss (R14-proven: wave-scan suffix sum) ----------
__global__ __launch_bounds__(256) void topk_loss(
    const unsigned short* __restrict__ simb,   // [CHUNK x NNEG]
    const float* __restrict__ z1, const float* __restrict__ z2,
    int rowOffset, float* __restrict__ rowloss)
{
    __shared__ int   hcnt[4096];
    __shared__ int   segc[256];
    __shared__ int   sufc[256];
    __shared__ int   wtot[4];
    __shared__ float fscratch[4];
    __shared__ int   iscratch[4];
    __shared__ int   sel_seg;
    __shared__ int   sh_bt, sh_run;

    const int tid = threadIdx.x;
    const int lane = tid & 63;
    const int wid = tid >> 6;
    const int grow = rowOffset + blockIdx.x;
    const unsigned short* srow = simb + (size_t)blockIdx.x * NNEG;

    #pragma unroll
    for (int j = 0; j < 16; j++) hcnt[tid * 16 + j] = 0;

    float p = z1[(size_t)grow * PROJ + tid] * z2[(size_t)grow * PROJ + tid];
    float pos = blockReduceSumF(p, fscratch);
    __syncthreads();

    // ---- pass 1: count histogram ----
    for (int i = tid * 8; i < NNEG; i += 256 * 8) {
        uint4 v4 = *(const uint4*)(srow + i);
        const unsigned short* u = (const unsigned short*)&v4;
        #pragma unroll
        for (int j = 0; j < 8; j++) {
            float v = b2f(u[j]);
            int k = (int)fmaf(v, 2048.f, 2048.f);
            k = min(max(k, 0), 4095);
            atomicAdd(&hcnt[k], 1);
        }
    }
    __syncthreads();

    int c = 0;
    #pragma unroll
    for (int j = 0; j < 16; j++) c += hcnt[tid * 16 + j];

    int v = c;
    #pragma unroll
    for (int o = 1; o < 64; o <<= 1) {
        int t = __shfl_down(v, o);
        if (lane + o < 64) v += t;
    }
    if (lane == 0) wtot[wid] = v;
    __syncthreads();
    int suf = v;
    #pragma unroll
    for (int w = 0; w < 4; w++) if (w > wid) suf += wtot[w];
    segc[tid] = c;
    sufc[tid] = suf;
    if (suf >= TOPK && suf - c < TOPK) sel_seg = tid;
    __syncthreads();

    if (tid == 0) {
        int t = sel_seg;
        int running = sufc[t] - segc[t];
        int bt = t * 16;
        for (int j = 15; j >= 0; j--) {
            int b = t * 16 + j;
            int cb = hcnt[b];
            if (running + cb >= TOPK) { bt = b; break; }
            running += cb;
        }
        sh_bt = bt; sh_run = running;
    }
    __syncthreads();
    const int bt = sh_bt;
    const float m = INV_T;

    // ---- pass 2: exp only above/at threshold bucket ----
    float s_above = 0.f, s_eq = 0.f;
    int c_eq = 0;
    for (int i = tid * 8; i < NNEG; i += 256 * 8) {
        uint4 v4 = *(const uint4*)(srow + i);
        const unsigned short* u = (const unsigned short*)&v4;
        #pragma unroll
        for (int j = 0; j < 8; j++) {
            float vv = b2f(u[j]);
            int k = (int)fmaf(vv, 2048.f, 2048.f);
            k = min(max(k, 0), 4095);
            if (k >= bt) {
                float e = __expf(fmaf(vv, INV_T, -m));
                if (k > bt) s_above += e;
                else { s_eq += e; c_eq++; }
            }
        }
    }
    s_above = blockReduceSumF(s_above, fscratch);
    __syncthreads();
    s_eq = blockReduceSumF(s_eq, fscratch);
    c_eq = blockReduceSumI(c_eq, iscratch);
    if (tid == 0) {
        int need = TOPK - sh_run;
        float avg = s_eq / (float)c_eq;
        float total = s_above + (float)need * avg + __expf(fmaf(pos, INV_T, -m));
        rowloss[grow] = m + logf(total) - pos * INV_T;
    }
}

__global__ __launch_bounds__(256) void loss_reduce(const float* __restrict__ rowloss,
                                                   float* __restrict__ out)
{
    __shared__ float scratch[4];
    float s = 0.f;
    for (int i = threadIdx.x; i < BATCH; i += 256) s += rowloss[i];
    s = blockReduceSumF(s, scratch);
    if (threadIdx.x == 0) out[0] = s / (float)BATCH;
}

// ---------- launcher ----------
extern "C" void kernel_launch(void* const* d_in, const int* in_sizes, int n_in,
                              void* d_out, int out_size, void* d_ws, size_t ws_size,
                              hipStream_t stream)
{
    const float* h1    = (const float*)d_in[0];
    const float* h2    = (const float*)d_in[1];
    const float* hneg  = (const float*)d_in[2];
    const float* W1    = (const float*)d_in[3];
    const float* b1    = (const float*)d_in[4];
    const float* gamma = (const float*)d_in[5];
    const float* beta  = (const float*)d_in[6];
    const float* W2    = (const float*)d_in[7];
    const float* b2    = (const float*)d_in[8];
    float* out = (float*)d_out;
    float* ws  = (float*)d_ws;

    // workspace layout (float offsets); total 50,604,032 f = 202.4 MB
    unsigned short* X_all = (unsigned short*)ws;                  // 40960x1024 bf16 = 20,971,520 f
    unsigned short* Yb    = (unsigned short*)(ws + 20971520);     // 40960x1024 bf16 = 20,971,520 f
    unsigned short* Z     = (unsigned short*)(ws + 41943040);     // 40960x256 bf16 (in-place norm)
    unsigned short* W1b   = (unsigned short*)(ws + 47185920);     // 1M bf16
    unsigned short* W2b   = (unsigned short*)(ws + 47710208);     // 256K bf16 (contiguous after W1b)
    float* partial = ws + 47841280;                               // 320*2048 = 655,360 f
    float* s_scale = ws + 48496640;                               // 3*1024
    float* s_shift = ws + 48499712;                               // 3*1024
    float* rowloss = ws + 48502784;                               // 4096
    float* Zfp     = ws + 48506880;                               // 8192x256 f32 = 2,097,152 f
    // overlay: simb spans X_all+Yb (both dead after GEMM2): 128 MB < 160 MB
    unsigned short* simb = X_all;

    // conversions (3 dispatches): W1+W2 pair, h1+h2 pair, h_neg
    // W1b and W2b are contiguous (1,048,576 + 262,144 elems), boundary at block 1024
    conv_f2b_pair<<<1280, 256, 0, stream>>>(W1, W2, W1b, HID * HID, HID * HID + PROJ * HID);
    // X_all[0:8M) = [h1; h2], boundary at block 2048
    conv_f2b8_pair<<<4096, 256, 0, stream>>>(h1, h2, X_all, BATCH * HID);
    conv_f2b8<<<16384, 256, 0, stream>>>(hneg, X_all + (size_t)2 * BATCH * HID);

    // GEMM1 (single dispatch): Yb = X_all @ W1b^T + b1
    {
        dim3 g(HID / BN, ROWS_TOTAL / BM);
        mfma_gemm<<<g, 256, 0, stream>>>(X_all, W1b, b1, Yb, ROWS_TOTAL, HID, HID);
    }

    // BN stats: single dispatch over all 320 row-blocks (layout matches reduce)
    bn_stats_partial<<<ROWS_TOTAL / BNS_ROWS, 256, 0, stream>>>(Yb, partial);
    bn_reduce_finalize<<<dim3(HID / 256, 3), 256, 0, stream>>>(partial, gamma, beta, s_scale, s_shift);

    // in-place BN + fast GELU on Yb
    bngelu<<<ROWS_TOTAL * HID / 8 / 256, 256, 0, stream>>>(Yb, s_scale, s_shift);

    // GEMM2 (single dispatch): Z = Yb @ W2b^T + b2
    {
        dim3 g(PROJ / BN, ROWS_TOTAL / BM);
        mfma_gemm<<<g, 256, 0, stream>>>(Yb, W2b, b2, Z, ROWS_TOTAL, PROJ, HID);
    }
    // L2 normalize in place (wave-per-row); fp32 copy of z1/z2
    l2norm<<<ROWS_TOTAL / 4, 256, 0, stream>>>(Z, Zfp);

    // sim chunks (2 x 2048 rows): sim = z1_chunk @ z_neg^T, then two-pass topk loss
    const unsigned short* znegb = Z + (size_t)(2 * BATCH) * PROJ;
    const float* z2v = Zfp + (size_t)BATCH * PROJ;
    for (int c = 0; c < BATCH / CHUNK; c++) {
        dim3 g(NNEG / BN, CHUNK / BM);
        mfma_gemm<<<g, 256, 0, stream>>>(Z + (size_t)(c * CHUNK) * PROJ, znegb, nullptr,
                                         simb, CHUNK, NNEG, PROJ);
        topk_loss<<<CHUNK, 256, 0, stream>>>(simb, Zfp, z2v, c * CHUNK, rowloss);
    }
    loss_reduce<<<1, 256, 0, stream>>>(rowloss, out);
}

// Round 23
// 509.057 us; speedup vs baseline: 1.1892x; 1.0090x over previous
//
#include <hip/hip_runtime.h>
#include <hip/hip_bf16.h>
#include <math.h>

#define BATCH 4096
#define NNEG 32768
#define HID 1024
#define PROJ 256
#define TOPK 128
#define ROWS_TOTAL 40960
#define CHUNK 2048
#define INV_T 14.2857142857142857f  // 1/0.07

#define BM 128
#define BN 128
#define BK 64

#define BNS_ROWS 128   // rows per bn_stats_partial block

#define CT_LD 136      // padded C-tile row stride (16B-aligned rows, conflict-lite)

typedef __attribute__((ext_vector_type(8))) short bf16x8;
typedef __attribute__((ext_vector_type(4))) float f32x4;

// ---------- helpers ----------
__device__ __forceinline__ float b2f(unsigned short u) {
    return __uint_as_float(((unsigned)u) << 16);
}
__device__ __forceinline__ unsigned short f2b(float f) {
    unsigned u = __float_as_uint(f);
    unsigned r = (u + 0x7FFFu + ((u >> 16) & 1u)) >> 16;  // RNE
    return (unsigned short)r;
}
// branchless tanh-GELU, exp2 form
__device__ __forceinline__ float gelu_fast(float v) {
    float v2 = v * v;
    float w = v * fmaf(v2, -0.1029433f, -2.3022086f);
    float e = exp2f(w);
    return v * __builtin_amdgcn_rcpf(1.0f + e);
}

__device__ __forceinline__ float blockReduceSumF(float v, volatile float* scratch) {
    #pragma unroll
    for (int o = 32; o > 0; o >>= 1) v += __shfl_down(v, o);
    int wid = threadIdx.x >> 6, lane = threadIdx.x & 63;
    __syncthreads();
    if (lane == 0) scratch[wid] = v;
    __syncthreads();
    return scratch[0] + scratch[1] + scratch[2] + scratch[3];
}
__device__ __forceinline__ int blockReduceSumI(int v, volatile int* scratch) {
    #pragma unroll
    for (int o = 32; o > 0; o >>= 1) v += __shfl_down(v, o);
    int wid = threadIdx.x >> 6, lane = threadIdx.x & 63;
    __syncthreads();
    if (lane == 0) scratch[wid] = v;
    __syncthreads();
    return scratch[0] + scratch[1] + scratch[2] + scratch[3];
}

// async global->LDS, 16B per lane; lds base must be wave-uniform
__device__ __forceinline__ void gl_lds16(const unsigned short* g, unsigned short* l) {
    __builtin_amdgcn_global_load_lds(
        (const __attribute__((address_space(1))) unsigned*)g,
        (__attribute__((address_space(3))) unsigned*)l, 16, 0, 0);
}

// ---------- fp32 -> bf16 conversions (pair variants: block-uniform src select) ----------
__global__ __launch_bounds__(256) void conv_f2b_pair(const float* __restrict__ a,
                                                     const float* __restrict__ b,
                                                     unsigned short* __restrict__ dst,
                                                     int half, int total)
{
    int i = (blockIdx.x * 256 + threadIdx.x) * 4;
    if (i >= total) return;
    const float* src = (i < half) ? (a + i) : (b + (i - half));
    float4 v = *(const float4*)src;
    ushort4 o;
    o.x = f2b(v.x); o.y = f2b(v.y); o.z = f2b(v.z); o.w = f2b(v.w);
    *(ushort4*)(dst + i) = o;
}

__global__ __launch_bounds__(256) void conv_f2b8_pair(const float* __restrict__ a,
                                                      const float* __restrict__ b,
                                                      unsigned short* __restrict__ dst,
                                                      int half)
{
    int i = (blockIdx.x * 256 + threadIdx.x) * 8;
    const float* src = (i < half) ? (a + i) : (b + (i - half));
    float4 x = *(const float4*)src;
    float4 y = *(const float4*)(src + 4);
    ushort4 o0, o1;
    o0.x = f2b(x.x); o0.y = f2b(x.y); o0.z = f2b(x.z); o0.w = f2b(x.w);
    o1.x = f2b(y.x); o1.y = f2b(y.y); o1.z = f2b(y.z); o1.w = f2b(y.w);
    *(ushort4*)(dst + i) = o0;
    *(ushort4*)(dst + i + 4) = o1;
}

__global__ __launch_bounds__(256) void conv_f2b8(const float* __restrict__ src,
                                                 unsigned short* __restrict__ dst)
{
    int i = (blockIdx.x * 256 + threadIdx.x) * 8;
    float4 a = *(const float4*)(src + i);
    float4 b = *(const float4*)(src + i + 4);
    ushort4 o0, o1;
    o0.x = f2b(a.x); o0.y = f2b(a.y); o0.z = f2b(a.z); o0.w = f2b(a.w);
    o1.x = f2b(b.x); o1.y = f2b(b.y); o1.z = f2b(b.z); o1.w = f2b(b.w);
    *(ushort4*)(dst + i) = o0;
    *(ushort4*)(dst + i + 4) = o1;
}

// ---------- XCD-chunked bijective swizzle (nwg % 8 == 0 in all launches) ----------
__device__ __forceinline__ void xcd_swizzle(int& bx, int& by) {
    int gx = gridDim.x;
    int orig = by * gx + bx;
    int q = (gx * gridDim.y) >> 3;
    int wg = (orig & 7) * q + (orig >> 3);
    bx = wg % gx;
    by = wg / gx;
}

// ---------- MFMA GEMM: single-buffer BK=64, 4 waves/SIMD, LDS-staged epilogue ----------
// smem is shared between the K-loop staging (As=smem[0:8192], Bs=smem[8192:16384])
// and the epilogue C-tile ([2][64][CT_LD], 17408 ushorts = 34.8 KB). The K-loop's
// final __syncthreads fences all As/Bs reads before the epilogue overwrites.
__global__ __launch_bounds__(256, 4) void mfma_gemm(
    const unsigned short* __restrict__ A, const unsigned short* __restrict__ Bw,
    const float* __restrict__ bias, unsigned short* __restrict__ C,
    int M, int N, int K)
{
    __shared__ unsigned short smem[2 * 64 * CT_LD];   // 17408 ushorts = 34.8 KB
    unsigned short* As = smem;            // 8192
    unsigned short* Bs = smem + BM * BK;  // 8192 (within smem)
    const int tid = threadIdx.x;
    int bxi = blockIdx.x, byi = blockIdx.y;
    xcd_swizzle(bxi, byi);
    const int bm = byi * BM;
    const int bn = bxi * BN;
    const int wave = tid >> 6;
    const int lane = tid & 63;
    const int wm = (wave >> 1) * 64;
    const int wn = (wave & 1) * 64;
    const int fr = lane & 15;
    const int fg = lane >> 4;

    int s_slot[4], s_row[4], s_c16[4];
    #pragma unroll
    for (int i = 0; i < 4; i++) {
        int s = wave * 256 + i * 64 + lane;
        s_slot[i] = (wave * 256 + i * 64) * 8;
        s_row[i] = s >> 3;
        s_c16[i] = (s & 7) ^ ((s >> 3) & 7);
    }

    f32x4 acc[4][4] = {};

    for (int k0 = 0; k0 < K; k0 += BK) {
        #pragma unroll
        for (int i = 0; i < 4; i++) {
            gl_lds16(A  + (size_t)(bm + s_row[i]) * K + k0 + s_c16[i] * 8, &As[s_slot[i]]);
            gl_lds16(Bw + (size_t)(bn + s_row[i]) * K + k0 + s_c16[i] * 8, &Bs[s_slot[i]]);
        }
        __syncthreads();
        #pragma unroll
        for (int ks = 0; ks < 2; ks++) {
            bf16x8 a[4], b[4];
            #pragma unroll
            for (int mi = 0; mi < 4; mi++) {
                int row = wm + mi * 16 + fr;
                a[mi] = *(const bf16x8*)&As[row * 64 + (((ks * 4 + fg) ^ (row & 7)) << 3)];
            }
            #pragma unroll
            for (int ni = 0; ni < 4; ni++) {
                int row = wn + ni * 16 + fr;
                b[ni] = *(const bf16x8*)&Bs[row * 64 + (((ks * 4 + fg) ^ (row & 7)) << 3)];
            }
            #pragma unroll
            for (int mi = 0; mi < 4; mi++)
                #pragma unroll
                for (int ni = 0; ni < 4; ni++)
                    acc[mi][ni] = __builtin_amdgcn_mfma_f32_16x16x32_bf16(a[mi], b[ni], acc[mi][ni], 0, 0, 0);
        }
        __syncthreads();
    }

    // ---- epilogue: stage C tile (f2b + bias) in LDS, then coalesced uint4 stores ----
    // Waves 0,1 (wm=0) own half 0; waves 2,3 (wm=64) own half 1. Cols disjoint via wn.
    {
        unsigned short* mybuf = smem + (wave >> 1) * (64 * CT_LD);
        #pragma unroll
        for (int mi = 0; mi < 4; mi++) {
            #pragma unroll
            for (int ni = 0; ni < 4; ni++) {
                int col = wn + ni * 16 + fr;
                float bv = bias ? bias[bn + col] : 0.0f;
                int rl0 = mi * 16 + fg * 4;
                #pragma unroll
                for (int r = 0; r < 4; r++) {
                    mybuf[(rl0 + r) * CT_LD + col] = f2b(acc[mi][ni][r] + bv);
                }
            }
        }
        __syncthreads();
        // wave w stores rows [32w, 32w+32): per iter 4 rows x 256B contiguous/row
        #pragma unroll
        for (int i = 0; i < 8; i++) {
            int row = wave * 32 + i * 4 + (lane >> 4);
            int colb = (lane & 15) * 8;
            uint4 v = *(const uint4*)&smem[(row >> 6) * (64 * CT_LD) + (row & 63) * CT_LD + colb];
            *(uint4*)&C[(size_t)(bm + row) * N + bn + colb] = v;
        }
    }
}

// ---------- BN stats, stage 1: single dispatch over all rows, atomic-free ----------
__global__ __launch_bounds__(256) void bn_stats_partial(const unsigned short* __restrict__ Yb,
                                                        float* __restrict__ partial)
{
    __shared__ float lsum[1024];
    __shared__ float lssq[1024];
    const int cg = (threadIdx.x & 127) * 8;
    int r = blockIdx.x * BNS_ROWS + (threadIdx.x >> 7);
    float s[8] = {}, ss[8] = {};
    #pragma unroll 4
    for (int i = 0; i < BNS_ROWS / 2; i++, r += 2) {
        uint4 v = *(const uint4*)&Yb[(size_t)r * HID + cg];
        const unsigned short* u = (const unsigned short*)&v;
        #pragma unroll
        for (int j = 0; j < 8; j++) {
            float f = b2f(u[j]);
            s[j] += f; ss[j] += f * f;
        }
    }
    if (threadIdx.x >= 128) {
        #pragma unroll
        for (int j = 0; j < 8; j++) { lsum[cg + j] = s[j]; lssq[cg + j] = ss[j]; }
    }
    __syncthreads();
    if (threadIdx.x < 128) {
        float* outs = partial + (size_t)blockIdx.x * 2048;
        #pragma unroll
        for (int j = 0; j < 8; j++) {
            outs[cg + j]        = s[j] + lsum[cg + j];
            outs[1024 + cg + j] = ss[j] + lssq[cg + j];
        }
    }
}

// ---------- BN stats, stage 2 ----------
__global__ __launch_bounds__(256) void bn_reduce_finalize(
    const float* __restrict__ partial,
    const float* __restrict__ gamma, const float* __restrict__ beta,
    float* __restrict__ scale, float* __restrict__ shift)
{
    int seg = blockIdx.y;
    int col = blockIdx.x * 256 + threadIdx.x;
    int base = (seg == 0) ? 0 : (seg == 1) ? 32 : 64;
    int nblk = (seg == 2) ? 256 : 32;
    const float* p = partial + (size_t)base * 2048;
    float s = 0.f, ss = 0.f;
    for (int b = 0; b < nblk; b++) {
        s  += p[(size_t)b * 2048 + col];
        ss += p[(size_t)b * 2048 + 1024 + col];
    }
    float n = (seg == 2) ? (float)NNEG : (float)BATCH;
    float mu = s / n;
    float var = ss / n - mu * mu;
    float sc = gamma[col] * rsqrtf(var + 1e-5f);
    scale[seg * HID + col] = sc;
    shift[seg * HID + col] = beta[col] - mu * sc;
}

// ---------- in-place BN + fast GELU over Yb (8 elems/thread) ----------
__global__ __launch_bounds__(256) void bngelu(unsigned short* __restrict__ Yb,
                                              const float* __restrict__ scale,
                                              const float* __restrict__ shift)
{
    size_t i = ((size_t)blockIdx.x * 256 + threadIdx.x) * 8;
    int row = (int)(i >> 10);
    int seg = (row < BATCH) ? 0 : (row < 2 * BATCH) ? 1 : 2;
    int col = (int)(i & 1023);
    float4 sc0 = *(const float4*)(scale + seg * HID + col);
    float4 sc1 = *(const float4*)(scale + seg * HID + col + 4);
    float4 sh0 = *(const float4*)(shift + seg * HID + col);
    float4 sh1 = *(const float4*)(shift + seg * HID + col + 4);
    float sc[8] = { sc0.x, sc0.y, sc0.z, sc0.w, sc1.x, sc1.y, sc1.z, sc1.w };
    float sh[8] = { sh0.x, sh0.y, sh0.z, sh0.w, sh1.x, sh1.y, sh1.z, sh1.w };
    uint4 v = *(uint4*)&Yb[i];
    unsigned short* u = (unsigned short*)&v;
    #pragma unroll
    for (int j = 0; j < 8; j++) {
        float f = fmaf(b2f(u[j]), sc[j], sh[j]);
        u[j] = f2b(gelu_fast(f));
    }
    *(uint4*)&Yb[i] = v;
}

// ---------- L2 normalize: wave-per-row (4 rows/block, no barriers) ----------
__global__ __launch_bounds__(256) void l2norm(unsigned short* __restrict__ Z,
                                              float* __restrict__ Zfp)
{
    const int lane = threadIdx.x & 63;
    const int w = threadIdx.x >> 6;
    size_t r = (size_t)blockIdx.x * 4 + w;
    unsigned short* zr = Z + r * PROJ + lane * 4;
    uint2 v2 = *(uint2*)zr;
    unsigned short* u = (unsigned short*)&v2;
    float f0 = b2f(u[0]), f1 = b2f(u[1]), f2 = b2f(u[2]), f3 = b2f(u[3]);
    float t = f0 * f0 + f1 * f1 + f2 * f2 + f3 * f3;
    #pragma unroll
    for (int o = 32; o > 0; o >>= 1) t += __shfl_down(t, o);
    t = __shfl(t, 0);
    float scale = 1.0f / fmaxf(sqrtf(t), 1e-12f);
    f0 *= scale; f1 *= scale; f2 *= scale; f3 *= scale;
    u[0] = f2b(f0); u[1] = f2b(f1); u[2] = f2b(f2); u[3] = f2b(f3);
    *(uint2*)zr = v2;
    if (r < 2 * BATCH) {
        float4 o4 = { f0, f1, f2, f3 };
        *(float4*)(Zfp + r * PROJ + lane * 4) = o4;
    }
}

// ---------- two-pass hist top-k loss (R14-proven: wave-scan suffix sum) ----------
__global__ __launch_bounds__(256) void topk_loss(
    const unsigned short* __restrict__ simb,   // [CHUNK x NNEG]
    const float* __restrict__ z1, const float* __restrict__ z2,
    int rowOffset, float* __restrict__ rowloss)
{
    __shared__ int   hcnt[4096];
    __shared__ int   segc[256];
    __shared__ int   sufc[256];
    __shared__ int   wtot[4];
    __shared__ float fscratch[4];
    __shared__ int   iscratch[4];
    __shared__ int   sel_seg;
    __shared__ int   sh_bt, sh_run;

    const int tid = threadIdx.x;
    const int lane = tid & 63;
    const int wid = tid >> 6;
    const int grow = rowOffset + blockIdx.x;
    const unsigned short* srow = simb + (size_t)blockIdx.x * NNEG;

    #pragma unroll
    for (int j = 0; j < 16; j++) hcnt[tid * 16 + j] = 0;

    float p = z1[(size_t)grow * PROJ + tid] * z2[(size_t)grow * PROJ + tid];
    float pos = blockReduceSumF(p, fscratch);
    __syncthreads();

    // ---- pass 1: count histogram ----
    for (int i = tid * 8; i < NNEG; i += 256 * 8) {
        uint4 v4 = *(const uint4*)(srow + i);
        const unsigned short* u = (const unsigned short*)&v4;
        #pragma unroll
        for (int j = 0; j < 8; j++) {
            float v = b2f(u[j]);
            int k = (int)fmaf(v, 2048.f, 2048.f);
            k = min(max(k, 0), 4095);
            atomicAdd(&hcnt[k], 1);
        }
    }
    __syncthreads();

    int c = 0;
    #pragma unroll
    for (int j = 0; j < 16; j++) c += hcnt[tid * 16 + j];

    int v = c;
    #pragma unroll
    for (int o = 1; o < 64; o <<= 1) {
        int t = __shfl_down(v, o);
        if (lane + o < 64) v += t;
    }
    if (lane == 0) wtot[wid] = v;
    __syncthreads();
    int suf = v;
    #pragma unroll
    for (int w = 0; w < 4; w++) if (w > wid) suf += wtot[w];
    segc[tid] = c;
    sufc[tid] = suf;
    if (suf >= TOPK && suf - c < TOPK) sel_seg = tid;
    __syncthreads();

    if (tid == 0) {
        int t = sel_seg;
        int running = sufc[t] - segc[t];
        int bt = t * 16;
        for (int j = 15; j >= 0; j--) {
            int b = t * 16 + j;
            int cb = hcnt[b];
            if (running + cb >= TOPK) { bt = b; break; }
            running += cb;
        }
        sh_bt = bt; sh_run = running;
    }
    __syncthreads();
    const int bt = sh_bt;
    const float m = INV_T;

    // ---- pass 2: exp only above/at threshold bucket ----
    float s_above = 0.f, s_eq = 0.f;
    int c_eq = 0;
    for (int i = tid * 8; i < NNEG; i += 256 * 8) {
        uint4 v4 = *(const uint4*)(srow + i);
        const unsigned short* u = (const unsigned short*)&v4;
        #pragma unroll
        for (int j = 0; j < 8; j++) {
            float vv = b2f(u[j]);
            int k = (int)fmaf(vv, 2048.f, 2048.f);
            k = min(max(k, 0), 4095);
            if (k >= bt) {
                float e = __expf(fmaf(vv, INV_T, -m));
                if (k > bt) s_above += e;
                else { s_eq += e; c_eq++; }
            }
        }
    }
    s_above = blockReduceSumF(s_above, fscratch);
    __syncthreads();
    s_eq = blockReduceSumF(s_eq, fscratch);
    c_eq = blockReduceSumI(c_eq, iscratch);
    if (tid == 0) {
        int need = TOPK - sh_run;
        float avg = s_eq / (float)c_eq;
        float total = s_above + (float)need * avg + __expf(fmaf(pos, INV_T, -m));
        rowloss[grow] = m + logf(total) - pos * INV_T;
    }
}

__global__ __launch_bounds__(256) void loss_reduce(const float* __restrict__ rowloss,
                                                   float* __restrict__ out)
{
    __shared__ float scratch[4];
    float s = 0.f;
    for (int i = threadIdx.x; i < BATCH; i += 256) s += rowloss[i];
    s = blockReduceSumF(s, scratch);
    if (threadIdx.x == 0) out[0] = s / (float)BATCH;
}

// ---------- launcher ----------
extern "C" void kernel_launch(void* const* d_in, const int* in_sizes, int n_in,
                              void* d_out, int out_size, void* d_ws, size_t ws_size,
                              hipStream_t stream)
{
    const float* h1    = (const float*)d_in[0];
    const float* h2    = (const float*)d_in[1];
    const float* hneg  = (const float*)d_in[2];
    const float* W1    = (const float*)d_in[3];
    const float* b1    = (const float*)d_in[4];
    const float* gamma = (const float*)d_in[5];
    const float* beta  = (const float*)d_in[6];
    const float* W2    = (const float*)d_in[7];
    const float* b2    = (const float*)d_in[8];
    float* out = (float*)d_out;
    float* ws  = (float*)d_ws;

    // workspace layout (float offsets); total 50,604,032 f = 202.4 MB
    unsigned short* X_all = (unsigned short*)ws;                  // 40960x1024 bf16 = 20,971,520 f
    unsigned short* Yb    = (unsigned short*)(ws + 20971520);     // 40960x1024 bf16 = 20,971,520 f
    unsigned short* Z     = (unsigned short*)(ws + 41943040);     // 40960x256 bf16 (in-place norm)
    unsigned short* W1b   = (unsigned short*)(ws + 47185920);     // 1M bf16
    unsigned short* W2b   = (unsigned short*)(ws + 47710208);     // 256K bf16 (contiguous after W1b)
    float* partial = ws + 47841280;                               // 320*2048 = 655,360 f
    float* s_scale = ws + 48496640;                               // 3*1024
    float* s_shift = ws + 48499712;                               // 3*1024
    float* rowloss = ws + 48502784;                               // 4096
    float* Zfp     = ws + 48506880;                               // 8192x256 f32 = 2,097,152 f
    // overlay: simb spans X_all+Yb (both dead after GEMM2): 128 MB < 160 MB
    unsigned short* simb = X_all;

    // conversions (3 dispatches): W1+W2 pair, h1+h2 pair, h_neg
    conv_f2b_pair<<<1280, 256, 0, stream>>>(W1, W2, W1b, HID * HID, HID * HID + PROJ * HID);
    conv_f2b8_pair<<<4096, 256, 0, stream>>>(h1, h2, X_all, BATCH * HID);
    conv_f2b8<<<16384, 256, 0, stream>>>(hneg, X_all + (size_t)2 * BATCH * HID);

    // GEMM1 (single dispatch): Yb = X_all @ W1b^T + b1
    {
        dim3 g(HID / BN, ROWS_TOTAL / BM);
        mfma_gemm<<<g, 256, 0, stream>>>(X_all, W1b, b1, Yb, ROWS_TOTAL, HID, HID);
    }

    // BN stats: single dispatch over all 320 row-blocks (layout matches reduce)
    bn_stats_partial<<<ROWS_TOTAL / BNS_ROWS, 256, 0, stream>>>(Yb, partial);
    bn_reduce_finalize<<<dim3(HID / 256, 3), 256, 0, stream>>>(partial, gamma, beta, s_scale, s_shift);

    // in-place BN + fast GELU on Yb
    bngelu<<<ROWS_TOTAL * HID / 8 / 256, 256, 0, stream>>>(Yb, s_scale, s_shift);

    // GEMM2 (single dispatch): Z = Yb @ W2b^T + b2
    {
        dim3 g(PROJ / BN, ROWS_TOTAL / BM);
        mfma_gemm<<<g, 256, 0, stream>>>(Yb, W2b, b2, Z, ROWS_TOTAL, PROJ, HID);
    }
    // L2 normalize in place (wave-per-row); fp32 copy of z1/z2
    l2norm<<<ROWS_TOTAL / 4, 256, 0, stream>>>(Z, Zfp);

    // sim chunks (2 x 2048 rows): sim = z1_chunk @ z_neg^T, then two-pass topk loss
    const unsigned short* znegb = Z + (size_t)(2 * BATCH) * PROJ;
    const float* z2v = Zfp + (size_t)BATCH * PROJ;
    for (int c = 0; c < BATCH / CHUNK; c++) {
        dim3 g(NNEG / BN, CHUNK / BM);
        mfma_gemm<<<g, 256, 0, stream>>>(Z + (size_t)(c * CHUNK) * PROJ, znegb, nullptr,
                                         simb, CHUNK, NNEG, PROJ);
        topk_loss<<<CHUNK, 256, 0, stream>>>(simb, Zfp, z2v, c * CHUNK, rowloss);
    }
    loss_reduce<<<1, 256, 0, stream>>>(rowloss, out);
}